// Round 12
// baseline (291.359 us; speedup 1.0000x reference)
//
#include <hip/hip_runtime.h>

#define NB 256
#define NT 512
#define NI 64
#define NH 256
#define NO 16

typedef __attribute__((ext_vector_type(8))) short short8;
typedef __attribute__((ext_vector_type(8))) __bf16 bf16x8;
typedef __attribute__((ext_vector_type(2))) float f32x2;
typedef __attribute__((ext_vector_type(4))) float f32x4;
typedef __attribute__((ext_vector_type(4))) int int4v;
typedef __attribute__((ext_vector_type(8))) int int8v;

__device__ __forceinline__ unsigned short f2bf(float f) {
  unsigned u = __builtin_bit_cast(unsigned, f);
  u += 0x7fffu + ((u >> 16) & 1u);          // round-to-nearest-even
  return (unsigned short)(u >> 16);
}

__device__ __forceinline__ f32x4 mfma16(short8 a, short8 b, f32x4 c) {
  return __builtin_amdgcn_mfma_f32_16x16x32_bf16(
      __builtin_bit_cast(bf16x8, a), __builtin_bit_cast(bf16x8, b), c, 0, 0, 0);
}

// MX fp4 K=128 MFMA; scales pinned to 1.0; cbsz=4/blgp=4 -> E2M1 both sides.
// Only v[0:3] of each 8-reg tuple is read; high halves stay loop-invariant 0.
__device__ __forceinline__ f32x4 mfma_fp4(int8v a, int8v b, f32x4 c) {
  return __builtin_amdgcn_mfma_scale_f32_16x16x128_f8f6f4(
      a, b, c, 4, 4, 0, 0x7f7f7f7f, 0, 0x7f7f7f7f);
}

// nearest e2m1 code, signed (preamble/W use)
__device__ __forceinline__ int fp4s(float v) {
  const float m = fabsf(v);
  int c;
  if (m < 1.75f)      c = (int)(m * 2.f + 0.5f);
  else if (m < 2.5f)  c = 4;
  else if (m < 3.5f)  c = 5;
  else if (m < 5.0f)  c = 6;
  else                c = 7;
  return c | (v < 0.f ? 8 : 0);
}

// nearest e2m1 code for v in [0,6] (h is post-ReLU/clamp: sign-free, branchless)
__device__ __forceinline__ int fp4u(float v) {
  int c = (int)fminf(v * 2.f + 0.5f, 3.f);          // codes 0..3 for v<1.75
  c = (v >= 1.75f) ? 4 : c;
  c = (v >= 2.5f)  ? 5 : c;
  c = (v >= 3.5f)  ? 6 : c;
  c = (v >= 5.0f)  ? 7 : c;
  return c;
}

__device__ __forceinline__ short8 pack8v(f32x4 lo, f32x4 hi) {
  short8 r;
#pragma unroll
  for (int i = 0; i < 4; ++i) {
    r[i]     = (short)f2bf(lo[i]);
    r[i + 4] = (short)f2bf(hi[i]);
  }
  return r;
}

__device__ __forceinline__ short8 pack8(const float* __restrict__ p) {
  return pack8v(*reinterpret_cast<const f32x4*>(p),
                *reinterpret_cast<const f32x4*>(p + 4));
}

// LDS-only barrier: drain DS ops, sync; global stores/loads stay in flight.
__device__ __forceinline__ void step_barrier() {
  asm volatile("s_waitcnt lgkmcnt(0)" ::: "memory");
  __builtin_amdgcn_s_barrier();
  asm volatile("" ::: "memory");
}

// One block per batch. 512 threads = 8 waves (2/SIMD).
// h2h via MX-fp4 K=128: A = broadcast h (fp4 x6, 128B nibble buffer), B =
// per-row-scaled Wh (fp4). 4 independent depth-1 MFMAs/wave/step (178cy/SIMD
// issue floor). Even/odd j-map: lane ll owns j = w*32+2*ll (+1). xi windows
// in registers; xi LDS split even/odd, stride 20 (bank-free reads).
__global__ __launch_bounds__(512, 2)
void rnn_fused(const float* __restrict__ x,  const float* __restrict__ Wi,
               const float* __restrict__ bi, const float* __restrict__ Wh,
               const float* __restrict__ bh, const float* __restrict__ Wo,
               const float* __restrict__ bo, const float* __restrict__ h0,
               float* __restrict__ dout)
{
  const int b   = blockIdx.x;
  const int tid = threadIdx.x;
  const int w   = tid >> 6;   // wave 0..7
  const int l   = tid & 63;   // lane
  const int lg  = l >> 4;     // 16-lane group
  const int ll  = l & 15;     // index within tile

  __shared__ __align__(16) unsigned char  hq4[2][128];      // fp4 h, nibbles
  __shared__ __align__(16) unsigned short rnnwin[16 * NH];  // 8 KB bf16 ring
  __shared__ __align__(16) float          xi_e[128 * 20];   // even j, [p][t]+pad
  __shared__ __align__(16) float          xi_o[128 * 20];   // odd  j

  float* outp = dout;                              // [B,T,O]
  float* hidp = dout + (size_t)NB * NT * NO;       // [B,H]
  float* rnnp = hidp + (size_t)NB * NH;            // [B,T,H]

  const f32x4 cz  = {0.f, 0.f, 0.f, 0.f};
  const int4v i4z = {0, 0, 0, 0};

  // ---- Wh -> fp4 B-fragments, per-row scale 6/m; row j = w*32+2*ll+jt,
  //      k = kc*128 + lg*32 + e (nibble e&1 of byte (kc*64+lg*16+e/2)) ----
  int8v wq4[2][2];
  float dq[2];
#pragma unroll
  for (int jt = 0; jt < 2; ++jt) {
    const int j = w * 32 + 2 * ll + jt;
    const float* wr = Wh + (size_t)j * NH;
    float m = 0.f;
#pragma unroll
    for (int kc = 0; kc < 2; ++kc)
#pragma unroll
      for (int e4 = 0; e4 < 8; ++e4) {
        f32x4 v = *reinterpret_cast<const f32x4*>(wr + kc * 128 + lg * 32 + e4 * 4);
#pragma unroll
        for (int i = 0; i < 4; ++i) m = fmaxf(m, fabsf(v[i]));
      }
    m = fmaxf(m, __shfl_xor(m, 16));
    m = fmaxf(m, __shfl_xor(m, 32));
    const float s = (m > 0.f) ? 6.f / m : 0.f;
    dq[jt] = m * (1.f / 36.f);
#pragma unroll
    for (int kc = 0; kc < 2; ++kc) {
      unsigned u[4] = {0u, 0u, 0u, 0u};
#pragma unroll
      for (int e = 0; e < 32; ++e) {
        const int code = fp4s(wr[kc * 128 + lg * 32 + e] * s);
        u[e >> 3] |= ((unsigned)code) << (4 * (e & 7));
      }
      int4v t4; t4[0] = (int)u[0]; t4[1] = (int)u[1]; t4[2] = (int)u[2]; t4[3] = (int)u[3];
      wq4[jt][kc] = __builtin_shufflevector(t4, i4z, 0, 1, 2, 3, 4, 5, 6, 7);
    }
  }

  // ---- bf16 i2h weights (16 VGPR); out-proj loaded per window ----
  short8 wif[2][2];
  float bregW[2];
#pragma unroll
  for (int jt = 0; jt < 2; ++jt) {
    const int j = w * 32 + jt * 16 + ll;
#pragma unroll
    for (int kx = 0; kx < 2; ++kx)
      wif[jt][kx] = pack8(Wi + (size_t)j * NI + kx * 32 + lg * 8);
    bregW[jt] = bi[j] + bh[j];          // bias folded at xi write
  }

  const int je = w * 32 + 2 * ll;      // even j this lane owns (+1 = odd)
  const int pj = w * 16 + ll;          // pair index je>>1
  const float bout = bo[ll];

  float h_reg0 = h0[je];
  float h_reg1 = h0[je + 1];

  // ---- init hq4[0] from h0 ----
  if (tid < 128) {
    const int q0 = fp4s(fminf(fmaxf(h0[2 * tid],     -1.f), 1.f) * 6.f);
    const int q1 = fp4s(fminf(fmaxf(h0[2 * tid + 1], -1.f), 1.f) * 6.f);
    hq4[0][tid] = (unsigned char)(q0 | (q1 << 4));
  }

  // ---- x prefetch (one window ahead): lane row ll, 16 f32 ----
  const float* xrow = x + (size_t)b * NT * NI + (size_t)ll * NI + lg * 8;
  f32x4 xpre[4];
  xpre[0] = *reinterpret_cast<const f32x4*>(xrow);
  xpre[1] = *reinterpret_cast<const f32x4*>(xrow + 4);
  xpre[2] = *reinterpret_cast<const f32x4*>(xrow + 32);
  xpre[3] = *reinterpret_cast<const f32x4*>(xrow + 36);

  __syncthreads();

  auto outproj = [&](int tbase) {    // out[tbase-16 .. tbase-1] from rnnwin
    f32x4 oacc = cz;
#pragma unroll
    for (int kt = 0; kt < 8; ++kt) {
      short8 wo = pack8(Wo + (size_t)ll * NH + kt * 32 + lg * 8);
      const char* ap = (const char*)rnnwin + ll * 512 +
                       ((kt * 64 + lg * 16) ^ (ll << 4));
      short8 af = *reinterpret_cast<const short8*>(ap);
      oacc = mfma16(af, wo, oacc);
    }
#pragma unroll
    for (int r = 0; r < 4; ++r) {
      const int tp = lg * 4 + r;
      outp[((size_t)b * NT + tbase - 16 + tp) * NO + ll] = oacc[r] + bout;
    }
  };

  // persistent fp4 A-tuples: high halves zeroed ONCE (loop-invariant)
  int8v A0, A1;
#pragma unroll
  for (int i = 4; i < 8; ++i) { A0[i] = 0; A1[i] = 0; }

#define STEP(TT, XIV0, XIV1)                                                   \
  {                                                                            \
    const int t    = (TT);                                                     \
    const int trow = t & 15;                                                   \
    const int p    = t & 1;                                                    \
    const unsigned char* hb = hq4[p];                                          \
    *(int4v*)&A0 = *(const int4v*)(hb + lg * 16);        /* kc=0 chunk */      \
    *(int4v*)&A1 = *(const int4v*)(hb + 64 + lg * 16);   /* kc=1 chunk */      \
    const float hx0 = h_reg0 + (XIV0);   /* xi carries bias */                 \
    const float hx1 = h_reg1 + (XIV1);                                         \
    f32x4 a00 = mfma_fp4(A0, wq4[0][0], cz);                                   \
    f32x4 a10 = mfma_fp4(A0, wq4[1][0], cz);                                   \
    f32x4 a01 = mfma_fp4(A1, wq4[0][1], cz);                                   \
    f32x4 a11 = mfma_fp4(A1, wq4[1][1], cz);                                   \
    const float s0 = a00[0] + a01[0];                                          \
    const float s1 = a10[0] + a11[0];                                          \
    const float a0 = __builtin_amdgcn_fmed3f(fmaf(s0, dq[0], hx0), 0.f, 1.f);  \
    const float a1 = __builtin_amdgcn_fmed3f(fmaf(s1, dq[1], hx1), 0.f, 1.f);  \
    h_reg0 = a0; h_reg1 = a1;                                                  \
    if (lg == 0) {                                                             \
      hq4[p ^ 1][pj] =                                                         \
          (unsigned char)(fp4u(a0 * 6.f) | (fp4u(a1 * 6.f) << 4));             \
      *(unsigned*)((char*)rnnwin + trow * 512 +                                \
                   ((4 * pj) ^ (trow << 4))) =                                 \
          (unsigned)f2bf(a0) | ((unsigned)f2bf(a1) << 16);                     \
      f32x2 o2; o2[0] = a0; o2[1] = a1;                                        \
      *(f32x2*)(rnnp + ((size_t)b * NT + t) * NH + je) = o2;                   \
    }                                                                          \
    step_barrier();                                                            \
  }

#pragma unroll 1
  for (int t0 = 0; t0 < NT; t0 += 16) {
    // ---- window boundary: rotating out-proj + i2h GEMM + x prefetch ----
    if (t0 > 0 && w == (((t0 >> 4) - 1) & 7)) outproj(t0);
    {
      short8 xf0 = pack8v(xpre[0], xpre[1]);
      short8 xf1 = pack8v(xpre[2], xpre[3]);
#pragma unroll
      for (int jt = 0; jt < 2; ++jt) {
        f32x4 acc = mfma16(xf0, wif[jt][0], cz);
        acc = mfma16(xf1, wif[jt][1], acc);
        const int j = w * 32 + jt * 16 + ll;
        float* xip = (j & 1) ? xi_o : xi_e;
        f32x4 xo;
#pragma unroll
        for (int r = 0; r < 4; ++r) xo[r] = acc[r] + bregW[jt];
        *(f32x4*)&xip[(j >> 1) * 20 + lg * 4] = xo;   // [pair][t], bias in
      }
    }
    if (t0 + 16 < NT) {
      const float* xp = x + (size_t)b * NT * NI + (size_t)(t0 + 16 + ll) * NI + lg * 8;
      xpre[0] = *reinterpret_cast<const f32x4*>(xp);
      xpre[1] = *reinterpret_cast<const f32x4*>(xp + 4);
      xpre[2] = *reinterpret_cast<const f32x4*>(xp + 32);
      xpre[3] = *reinterpret_cast<const f32x4*>(xp + 36);
    }
    step_barrier();

    // ---- whole window's xi into registers (statically indexed below) ----
    f32x4 xqe[4], xqo[4];
#pragma unroll
    for (int q = 0; q < 4; ++q) {
      xqe[q] = *(const f32x4*)&xi_e[pj * 20 + q * 4];
      xqo[q] = *(const f32x4*)&xi_o[pj * 20 + q * 4];
    }

    STEP(t0 + 0,  xqe[0][0], xqo[0][0]) STEP(t0 + 1,  xqe[0][1], xqo[0][1])
    STEP(t0 + 2,  xqe[0][2], xqo[0][2]) STEP(t0 + 3,  xqe[0][3], xqo[0][3])
    STEP(t0 + 4,  xqe[1][0], xqo[1][0]) STEP(t0 + 5,  xqe[1][1], xqo[1][1])
    STEP(t0 + 6,  xqe[1][2], xqo[1][2]) STEP(t0 + 7,  xqe[1][3], xqo[1][3])
    STEP(t0 + 8,  xqe[2][0], xqo[2][0]) STEP(t0 + 9,  xqe[2][1], xqo[2][1])
    STEP(t0 + 10, xqe[2][2], xqo[2][2]) STEP(t0 + 11, xqe[2][3], xqo[2][3])
    STEP(t0 + 12, xqe[3][0], xqo[3][0]) STEP(t0 + 13, xqe[3][1], xqo[3][1])
    STEP(t0 + 14, xqe[3][2], xqo[3][2]) STEP(t0 + 15, xqe[3][3], xqo[3][3])
  }
#undef STEP

  // ---- epilogue: final window out-proj (rotation slot 31&7 = 7) + hidden ----
  if (w == 7) outproj(NT);
  if (lg == 0) {
    f32x2 h2; h2[0] = h_reg0; h2[1] = h_reg1;
    *(f32x2*)(hidp + (size_t)b * NH + je) = h2;
  }
}

extern "C" void kernel_launch(void* const* d_in, const int* in_sizes, int n_in,
                              void* d_out, int out_size, void* d_ws, size_t ws_size,
                              hipStream_t stream) {
  const float* x  = (const float*)d_in[0];
  const float* Wi = (const float*)d_in[1];
  const float* bi = (const float*)d_in[2];
  const float* Wh = (const float*)d_in[3];
  const float* bh = (const float*)d_in[4];
  const float* Wo = (const float*)d_in[5];
  const float* bo = (const float*)d_in[6];
  const float* h0 = (const float*)d_in[7];
  rnn_fused<<<dim3(NB), dim3(512), 0, stream>>>(x, Wi, bi, Wh, bh, Wo, bo, h0,
                                                (float*)d_out);
}

// Round 13
// 189.730 us; speedup vs baseline: 1.5357x; 1.5357x over previous
//
#include <hip/hip_runtime.h>

#define NB 256
#define NT 512
#define NI 64
#define NH 256
#define NO 16

typedef __attribute__((ext_vector_type(8))) short short8;
typedef __attribute__((ext_vector_type(8))) __bf16 bf16x8;
typedef __attribute__((ext_vector_type(2))) float f32x2;
typedef __attribute__((ext_vector_type(4))) float f32x4;
typedef __attribute__((ext_vector_type(4))) int int4v;

__device__ __forceinline__ unsigned short f2bf(float f) {
  unsigned u = __builtin_bit_cast(unsigned, f);
  u += 0x7fffu + ((u >> 16) & 1u);          // round-to-nearest-even
  return (unsigned short)(u >> 16);
}

__device__ __forceinline__ f32x4 mfma16(short8 a, short8 b, f32x4 c) {
  return __builtin_amdgcn_mfma_f32_16x16x32_bf16(
      __builtin_bit_cast(bf16x8, a), __builtin_bit_cast(bf16x8, b), c, 0, 0, 0);
}

// i8 MFMA, K=64: A 16 i8/lane (4 VGPR), B 16 i8/lane, C/D 4 i32. Exact i32 acc.
__device__ __forceinline__ int4v mfma_i8(int4v a, int4v b, int4v c) {
  return __builtin_amdgcn_mfma_i32_16x16x64_i8(a, b, c, 0, 0, 0);
}

__device__ __forceinline__ short8 pack8v(f32x4 lo, f32x4 hi) {
  short8 r;
#pragma unroll
  for (int i = 0; i < 4; ++i) {
    r[i]     = (short)f2bf(lo[i]);
    r[i + 4] = (short)f2bf(hi[i]);
  }
  return r;
}

__device__ __forceinline__ short8 pack8(const float* __restrict__ p) {
  return pack8v(*reinterpret_cast<const f32x4*>(p),
                *reinterpret_cast<const f32x4*>(p + 4));
}

// LDS-only barrier: drain DS ops, sync; global stores/loads stay in flight.
__device__ __forceinline__ void step_barrier() {
  asm volatile("s_waitcnt lgkmcnt(0)" ::: "memory");
  __builtin_amdgcn_s_barrier();
  asm volatile("" ::: "memory");
}

// One block per batch. 512 threads = 8 waves (2/SIMD).  [R6 structure]
// Wave w owns hidden cols j in [w*32, w*32+32) as 2 j-tiles.
// h2h via i8 K=64 MFMA: A = broadcast h_q (i8 chunk buffer, 4 b128 reads),
// B = per-row-scaled Wh_q (i8 in VGPRs); 4 independent depth-2 chains.
// xi for each window in REGISTERS (bias folded at the [j][t] write).
__global__ __launch_bounds__(512, 2)
void rnn_fused(const float* __restrict__ x,  const float* __restrict__ Wi,
               const float* __restrict__ bi, const float* __restrict__ Wh,
               const float* __restrict__ bh, const float* __restrict__ Wo,
               const float* __restrict__ bo, const float* __restrict__ h0,
               float* __restrict__ dout)
{
  const int b   = blockIdx.x;
  const int tid = threadIdx.x;
  const int w   = tid >> 6;   // wave 0..7
  const int l   = tid & 63;   // lane
  const int lg  = l >> 4;     // 16-lane group
  const int ll  = l & 15;     // index within tile

  __shared__ __align__(16) signed char    hq[2][256];       // i8 h, chunk layout
  __shared__ __align__(16) unsigned short rnnwin[16 * NH];  // 8 KB bf16 ring
  __shared__ __align__(16) float          xi_lds[NH][20];   // [j][t(16)+pad4]

  float* outp = dout;                              // [B,T,O]
  float* hidp = dout + (size_t)NB * NT * NO;       // [B,H]
  float* rnnp = hidp + (size_t)NB * NH;            // [B,T,H]

  const f32x4 cz = {0.f, 0.f, 0.f, 0.f};
  const int4v iz = {0, 0, 0, 0};

  // ---- Wh -> i8 B-fragments, per-row scale 127/m: lane holds col n=ll
  //      (row j = w*32 + jt*16 + ll), k = kt*64 + lg*16 + e ----
  int4v whq[2][4];
  float dq[2];
#pragma unroll
  for (int jt = 0; jt < 2; ++jt) {
    const int j = w * 32 + jt * 16 + ll;
    const float* wr = Wh + (size_t)j * NH;
    float m = 0.f;
#pragma unroll
    for (int kt = 0; kt < 4; ++kt)
#pragma unroll
      for (int e4 = 0; e4 < 4; ++e4) {
        f32x4 v = *reinterpret_cast<const f32x4*>(wr + kt * 64 + lg * 16 + e4 * 4);
#pragma unroll
        for (int i = 0; i < 4; ++i) m = fmaxf(m, fabsf(v[i]));
      }
    m = fmaxf(m, __shfl_xor(m, 16));
    m = fmaxf(m, __shfl_xor(m, 32));
    const float inv = (m > 0.f) ? 127.f / m : 0.f;
    dq[jt] = m / (127.f * 127.f);
#pragma unroll
    for (int kt = 0; kt < 4; ++kt) {
      unsigned u[4] = {0u, 0u, 0u, 0u};
#pragma unroll
      for (int e = 0; e < 16; ++e) {
        const float v = wr[kt * 64 + lg * 16 + e] * inv;
        int q = (int)(v + (v >= 0.f ? 0.5f : -0.5f));
        q = q > 127 ? 127 : (q < -127 ? -127 : q);
        u[e >> 2] |= ((unsigned)(q & 255)) << (8 * (e & 3));
      }
      int4v t; t[0] = (int)u[0]; t[1] = (int)u[1]; t[2] = (int)u[2]; t[3] = (int)u[3];
      whq[jt][kt] = t;
    }
  }

  // ---- bf16 i2h weights (16 VGPR); out-proj weights loaded per window ----
  short8 wif[2][2];
  float bregW[2];
#pragma unroll
  for (int jt = 0; jt < 2; ++jt) {
    const int j = w * 32 + jt * 16 + ll;
#pragma unroll
    for (int kx = 0; kx < 2; ++kx)
      wif[jt][kx] = pack8(Wi + (size_t)j * NI + kx * 32 + lg * 8);
    bregW[jt] = bi[j] + bh[j];            // bias folded at xi write
  }
  const float bout = bo[ll];

  float h_reg0 = h0[w * 32 + ll];
  float h_reg1 = h0[w * 32 + 16 + ll];

  // writer lanes (lg<2): own j = w*32 + lg*16 + ll
  const int  jw     = w * 32 + lg * 16 + ll;
  const int  widx   = ((jw >> 6) << 6) | (((jw >> 4) & 3) << 4) | (jw & 15);
  const bool wr_act = (lg < 2);

  // ---- init hq[0] from h0 (chunk layout) ----
  if (tid < 256) {
    const int jj  = tid;
    const int wi2 = ((jj >> 6) << 6) | (((jj >> 4) & 3) << 4) | (jj & 15);
    float hv = fminf(fmaxf(h0[jj], -1.f), 1.f);
    hq[0][wi2] = (signed char)(int)(hv * 127.f + (hv >= 0.f ? 0.5f : -0.5f));
  }

  // ---- x prefetch (one window ahead): lane row ll, 16 f32 ----
  const float* xrow = x + (size_t)b * NT * NI + (size_t)ll * NI + lg * 8;
  f32x4 xpre[4];
  xpre[0] = *reinterpret_cast<const f32x4*>(xrow);
  xpre[1] = *reinterpret_cast<const f32x4*>(xrow + 4);
  xpre[2] = *reinterpret_cast<const f32x4*>(xrow + 32);
  xpre[3] = *reinterpret_cast<const f32x4*>(xrow + 36);

  __syncthreads();

  const int j0 = w * 32 + ll;        // jt=0 row
  const int j1 = w * 32 + 16 + ll;   // jt=1 row

  auto outproj = [&](int tbase) {    // out[tbase-16 .. tbase-1] from rnnwin
    f32x4 oacc = cz;
#pragma unroll
    for (int kt = 0; kt < 8; ++kt) {
      short8 wo = pack8(Wo + (size_t)ll * NH + kt * 32 + lg * 8);
      const char* ap = (const char*)rnnwin + ll * 512 +
                       ((kt * 64 + lg * 16) ^ (ll << 4));
      short8 af = *reinterpret_cast<const short8*>(ap);
      oacc = mfma16(af, wo, oacc);
    }
#pragma unroll
    for (int r = 0; r < 4; ++r) {
      const int tp = lg * 4 + r;
      outp[((size_t)b * NT + tbase - 16 + tp) * NO + ll] = oacc[r] + bout;
    }
  };

#define STEP(TT, XIV0, XIV1)                                                   \
  {                                                                            \
    const int t    = (TT);                                                     \
    const int trow = t & 15;                                                   \
    const int p    = t & 1;                                                    \
    int4v ha[4];                                                               \
    _Pragma("unroll")                                                          \
    for (int kt = 0; kt < 4; ++kt)                                             \
      ha[kt] = *(const int4v*)&hq[p][kt * 64 + lg * 16];                       \
    /* 4 independent depth-2 chains; i32 accumulation is exact */              \
    int4v a0a = mfma_i8(ha[0], whq[0][0], iz);                                 \
    int4v a0b = mfma_i8(ha[2], whq[0][2], iz);                                 \
    int4v a1a = mfma_i8(ha[0], whq[1][0], iz);                                 \
    int4v a1b = mfma_i8(ha[2], whq[1][2], iz);                                 \
    a0a = mfma_i8(ha[1], whq[0][1], a0a);                                     \
    a0b = mfma_i8(ha[3], whq[0][3], a0b);                                     \
    a1a = mfma_i8(ha[1], whq[1][1], a1a);                                     \
    a1b = mfma_i8(ha[3], whq[1][3], a1b);                                     \
    const float hx0 = h_reg0 + (XIV0);   /* xi carries bias */                 \
    const float hx1 = h_reg1 + (XIV1);                                         \
    const float s0 = (float)(a0a[0] + a0b[0]);                                 \
    const float s1 = (float)(a1a[0] + a1b[0]);                                 \
    const float a0 = __builtin_amdgcn_fmed3f(fmaf(s0, dq[0], hx0), 0.f, 1.f);  \
    const float a1 = __builtin_amdgcn_fmed3f(fmaf(s1, dq[1], hx1), 0.f, 1.f);  \
    h_reg0 = a0; h_reg1 = a1;                                                  \
    if (wr_act) {                                                              \
      const float aw = lg ? a1 : a0;                                           \
      hq[p ^ 1][widx] = (signed char)(int)(aw * 127.f + 0.5f);                 \
      const int byte = trow * 512 + ((2 * jw) ^ (trow << 4));                  \
      rnnwin[byte >> 1] = f2bf(aw);                                            \
      rnnp[((size_t)b * NT + t) * NH + jw] = aw;                               \
    }                                                                          \
    step_barrier();                                                            \
  }

#pragma unroll 1
  for (int t0 = 0; t0 < NT; t0 += 16) {
    // ---- window boundary: rotating out-proj + i2h GEMM + x prefetch ----
    if (t0 > 0 && w == (((t0 >> 4) - 1) & 7)) outproj(t0);
    {
      short8 xf0 = pack8v(xpre[0], xpre[1]);
      short8 xf1 = pack8v(xpre[2], xpre[3]);
#pragma unroll
      for (int jt = 0; jt < 2; ++jt) {
        f32x4 acc = mfma16(xf0, wif[jt][0], cz);
        acc = mfma16(xf1, wif[jt][1], acc);
        const int j = w * 32 + jt * 16 + ll;
        f32x4 xo;
#pragma unroll
        for (int r = 0; r < 4; ++r) xo[r] = acc[r] + bregW[jt];
        *(f32x4*)&xi_lds[j][lg * 4] = xo;   // rows r -> t = lg*4 + r
      }
    }
    if (t0 + 16 < NT) {
      const float* xp = x + (size_t)b * NT * NI + (size_t)(t0 + 16 + ll) * NI + lg * 8;
      xpre[0] = *reinterpret_cast<const f32x4*>(xp);
      xpre[1] = *reinterpret_cast<const f32x4*>(xp + 4);
      xpre[2] = *reinterpret_cast<const f32x4*>(xp + 32);
      xpre[3] = *reinterpret_cast<const f32x4*>(xp + 36);
    }
    step_barrier();

    // ---- whole window's xi into registers (statically indexed below) ----
    f32x4 xqA[4], xqB[4];
#pragma unroll
    for (int q = 0; q < 4; ++q) {
      xqA[q] = *(const f32x4*)&xi_lds[j0][q * 4];
      xqB[q] = *(const f32x4*)&xi_lds[j1][q * 4];
    }

    STEP(t0 + 0,  xqA[0][0], xqB[0][0]) STEP(t0 + 1,  xqA[0][1], xqB[0][1])
    STEP(t0 + 2,  xqA[0][2], xqB[0][2]) STEP(t0 + 3,  xqA[0][3], xqB[0][3])
    STEP(t0 + 4,  xqA[1][0], xqB[1][0]) STEP(t0 + 5,  xqA[1][1], xqB[1][1])
    STEP(t0 + 6,  xqA[1][2], xqB[1][2]) STEP(t0 + 7,  xqA[1][3], xqB[1][3])
    STEP(t0 + 8,  xqA[2][0], xqB[2][0]) STEP(t0 + 9,  xqA[2][1], xqB[2][1])
    STEP(t0 + 10, xqA[2][2], xqB[2][2]) STEP(t0 + 11, xqA[2][3], xqB[2][3])
    STEP(t0 + 12, xqA[3][0], xqB[3][0]) STEP(t0 + 13, xqA[3][1], xqB[3][1])
    STEP(t0 + 14, xqA[3][2], xqB[3][2]) STEP(t0 + 15, xqA[3][3], xqB[3][3])
  }
#undef STEP

  // ---- epilogue: final window out-proj (rotation slot 31&7 = 7) + hidden ----
  if (w == 7) outproj(NT);
  if (wr_act) {
    const float aw = lg ? h_reg1 : h_reg0;
    hidp[(size_t)b * NH + jw] = aw;
  }
}

extern "C" void kernel_launch(void* const* d_in, const int* in_sizes, int n_in,
                              void* d_out, int out_size, void* d_ws, size_t ws_size,
                              hipStream_t stream) {
  const float* x  = (const float*)d_in[0];
  const float* Wi = (const float*)d_in[1];
  const float* bi = (const float*)d_in[2];
  const float* Wh = (const float*)d_in[3];
  const float* bh = (const float*)d_in[4];
  const float* Wo = (const float*)d_in[5];
  const float* bo = (const float*)d_in[6];
  const float* h0 = (const float*)d_in[7];
  rnn_fused<<<dim3(NB), dim3(512), 0, stream>>>(x, Wi, bi, Wh, bh, Wo, bo, h0,
                                                (float*)d_out);
}